// Round 1
// baseline (1994.517 us; speedup 1.0000x reference)
//
#include <hip/hip_runtime.h>
#include <cstddef>

// SNN: 4x (Linear + LIF), B=128, T=64, dims 2048->2048->2048->1024->128.
// Key insight: recurrence is elementwise per neuron; layers factorize into
// 4 big dense fp32 GEMMs ([B*T, K] @ [N, K]^T) + 4 elementwise LIF scans.
// fp32 only: spike threshold (mem > 1) is bit-sensitive, no bf16/MFMA.

#define BETA 0.95f

static constexpr int B_ = 128;
static constexpr int T_ = 64;
static constexpr int M_ = B_ * T_;       // 8192 rows
static constexpr int NIN = 2048;
static constexpr int H1 = 2048;
static constexpr int H2 = 1024;
static constexpr int NOUT = 128;

// ---------------------------------------------------------------------------
// C[m][n] = sum_k A[m][k] * W[n][k] + bias[n]
// A: [M, K] row-major; W: [N, K] row-major (i.e. computes A @ W^T + b).
// Tile 128x128, BK=16, 256 threads, 8x8 micro-tile as 2x2 float4 groups.
// ---------------------------------------------------------------------------
__global__ __launch_bounds__(256) void sgemm_nt_bias(
    const float* __restrict__ A, const float* __restrict__ W,
    const float* __restrict__ bias, float* __restrict__ C,
    int M, int N, int K)
{
    constexpr int BM = 128, BN = 128, BK = 16;
    __shared__ float As[BK][BM + 4];
    __shared__ float Ws[BK][BN + 4];

    const int tid = threadIdx.x;
    const int tx = tid & 15;   // 0..15 -> col groups
    const int ty = tid >> 4;   // 0..15 -> row groups
    const int bm = blockIdx.y * BM;
    const int bn = blockIdx.x * BN;

    const int lr = tid >> 2;   // 0..63 row for staging loads
    const int lc = tid & 3;    // float4 index along K

    float acc[8][8];
#pragma unroll
    for (int i = 0; i < 8; ++i)
#pragma unroll
        for (int j = 0; j < 8; ++j) acc[i][j] = 0.f;

    for (int k0 = 0; k0 < K; k0 += BK) {
        // Stage A tile (128 rows x 16 k) transposed into LDS: As[k][m]
#pragma unroll
        for (int i = 0; i < 2; ++i) {
            int r = lr + i * 64;
            float4 v = *reinterpret_cast<const float4*>(
                &A[(size_t)(bm + r) * K + k0 + lc * 4]);
            As[lc * 4 + 0][r] = v.x;
            As[lc * 4 + 1][r] = v.y;
            As[lc * 4 + 2][r] = v.z;
            As[lc * 4 + 3][r] = v.w;
        }
#pragma unroll
        for (int i = 0; i < 2; ++i) {
            int r = lr + i * 64;
            float4 v = *reinterpret_cast<const float4*>(
                &W[(size_t)(bn + r) * K + k0 + lc * 4]);
            Ws[lc * 4 + 0][r] = v.x;
            Ws[lc * 4 + 1][r] = v.y;
            Ws[lc * 4 + 2][r] = v.z;
            Ws[lc * 4 + 3][r] = v.w;
        }
        __syncthreads();

#pragma unroll
        for (int kk = 0; kk < BK; ++kk) {
            float a[8], w[8];
            *reinterpret_cast<float4*>(&a[0]) =
                *reinterpret_cast<const float4*>(&As[kk][ty * 4]);
            *reinterpret_cast<float4*>(&a[4]) =
                *reinterpret_cast<const float4*>(&As[kk][64 + ty * 4]);
            *reinterpret_cast<float4*>(&w[0]) =
                *reinterpret_cast<const float4*>(&Ws[kk][tx * 4]);
            *reinterpret_cast<float4*>(&w[4]) =
                *reinterpret_cast<const float4*>(&Ws[kk][64 + tx * 4]);
#pragma unroll
            for (int i = 0; i < 8; ++i)
#pragma unroll
                for (int j = 0; j < 8; ++j)
                    acc[i][j] += a[i] * w[j];
        }
        __syncthreads();
    }

    // Epilogue: rows {bm + ih*64 + ty*4 + i}, cols {bn + jh*64 + tx*4 ..+3}
#pragma unroll
    for (int ih = 0; ih < 2; ++ih) {
#pragma unroll
        for (int i = 0; i < 4; ++i) {
            int r = bm + ih * 64 + ty * 4 + i;
#pragma unroll
            for (int jh = 0; jh < 2; ++jh) {
                int c = bn + jh * 64 + tx * 4;
                float4 bv = *reinterpret_cast<const float4*>(&bias[c]);
                float4 v;
                v.x = acc[ih * 4 + i][jh * 4 + 0] + bv.x;
                v.y = acc[ih * 4 + i][jh * 4 + 1] + bv.y;
                v.z = acc[ih * 4 + i][jh * 4 + 2] + bv.z;
                v.w = acc[ih * 4 + i][jh * 4 + 3] + bv.w;
                *reinterpret_cast<float4*>(&C[(size_t)r * N + c]) = v;
            }
        }
    }
}

// ---------------------------------------------------------------------------
// LIF scan over T, in place: buf[b][t][n] holds currents on input, spikes
// (0.0/1.0) on output. One thread per (b, n); t-loop is the recurrence.
// Rounding matches numpy: ((beta*mem) + cur) - reset, each step rounded.
// ---------------------------------------------------------------------------
__global__ __launch_bounds__(256) void lif_scan_inplace(
    float* __restrict__ buf, int N, int total)
{
    int g = blockIdx.x * blockDim.x + threadIdx.x;
    if (g >= total) return;
    int b = g / N;
    int n = g - b * N;
    size_t base = (size_t)b * T_ * N + n;

    float mem = 0.f;
    for (int t = 0; t < T_; ++t) {
        size_t idx = base + (size_t)t * N;
        float cur = buf[idx];
        float reset = ((mem - 1.0f) > 0.0f) ? 1.0f : 0.0f;
        mem = __fmul_rn(BETA, mem);
        mem = __fadd_rn(mem, cur);
        mem = __fadd_rn(mem, -reset);
        buf[idx] = ((mem - 1.0f) > 0.0f) ? 1.0f : 0.0f;
    }
}

// Final layer: emit both spk3 and mem3 into d_out.
__global__ __launch_bounds__(256) void lif_scan_final(
    const float* __restrict__ cur_in, float* __restrict__ spk_out,
    float* __restrict__ mem_out, int N, int total)
{
    int g = blockIdx.x * blockDim.x + threadIdx.x;
    if (g >= total) return;
    int b = g / N;
    int n = g - b * N;
    size_t base = (size_t)b * T_ * N + n;

    float mem = 0.f;
    for (int t = 0; t < T_; ++t) {
        size_t idx = base + (size_t)t * N;
        float cur = cur_in[idx];
        float reset = ((mem - 1.0f) > 0.0f) ? 1.0f : 0.0f;
        mem = __fmul_rn(BETA, mem);
        mem = __fadd_rn(mem, cur);
        mem = __fadd_rn(mem, -reset);
        spk_out[idx] = ((mem - 1.0f) > 0.0f) ? 1.0f : 0.0f;
        mem_out[idx] = mem;
    }
}

extern "C" void kernel_launch(void* const* d_in, const int* in_sizes, int n_in,
                              void* d_out, int out_size, void* d_ws, size_t ws_size,
                              hipStream_t stream)
{
    const float* x  = (const float*)d_in[0];
    const float* W0 = (const float*)d_in[1];
    const float* b0 = (const float*)d_in[2];
    const float* W1 = (const float*)d_in[3];
    const float* b1 = (const float*)d_in[4];
    const float* W2 = (const float*)d_in[5];
    const float* b2 = (const float*)d_in[6];
    const float* W3 = (const float*)d_in[7];
    const float* b3 = (const float*)d_in[8];
    float* out = (float*)d_out;

    // Workspace: two ping-pong buffers of M_*2048 floats (64 MiB each).
    float* bufA = (float*)d_ws;
    float* bufB = bufA + (size_t)M_ * 2048;

    dim3 blk(256);

    // Layer 0: cur0 = x @ W0^T + b0  -> bufA ; LIF in place -> s0
    {
        dim3 grid(NIN / 128, M_ / 128);  // (16, 64)
        sgemm_nt_bias<<<grid, blk, 0, stream>>>(x, W0, b0, bufA, M_, NIN, NIN);
        int total = B_ * NIN;
        lif_scan_inplace<<<total / 256, blk, 0, stream>>>(bufA, NIN, total);
    }
    // Layer 1: cur1 = s0 @ W1^T + b1 -> bufB ; LIF -> s1
    {
        dim3 grid(H1 / 128, M_ / 128);
        sgemm_nt_bias<<<grid, blk, 0, stream>>>(bufA, W1, b1, bufB, M_, H1, NIN);
        int total = B_ * H1;
        lif_scan_inplace<<<total / 256, blk, 0, stream>>>(bufB, H1, total);
    }
    // Layer 2: cur2 = s1 @ W2^T + b2 -> bufA ; LIF -> s2
    {
        dim3 grid(H2 / 128, M_ / 128);
        sgemm_nt_bias<<<grid, blk, 0, stream>>>(bufB, W2, b2, bufA, M_, H2, H1);
        int total = B_ * H2;
        lif_scan_inplace<<<total / 256, blk, 0, stream>>>(bufA, H2, total);
    }
    // Layer 3: cur3 = s2 @ W3^T + b3 -> bufB ; final LIF -> d_out
    {
        dim3 grid(NOUT / 128, M_ / 128);  // (1, 64)
        sgemm_nt_bias<<<grid, blk, 0, stream>>>(bufA, W3, b3, bufB, M_, NOUT, H2);
        int total = B_ * NOUT;
        float* spk3 = out;
        float* mem3 = out + (size_t)M_ * NOUT;
        lif_scan_final<<<total / 256, blk, 0, stream>>>(bufB, spk3, mem3, NOUT, total);
    }
}

// Round 5
// 1015.670 us; speedup vs baseline: 1.9637x; 1.9637x over previous
//
#include <hip/hip_runtime.h>
#include <cstddef>
#include <cstdint>

// SNN: 4x (Linear + LIF). GEMMs on the bf16 matrix pipe via EXACT 3-term
// bf16 splitting, with SCALE-SEGREGATED accumulation:
//   main GEMM:  sum of 8-bit-mantissa products at scale 1  (near-exact fp32)
//   corr GEMM:  all correction cross-terms chained in one accumulator whose
//               running magnitude is ~2^-9 (near-exact at its own scale),
//               then curM += corr (single rounding).
// LIF adds bias (single rounding) -> matches reference (matmul + b) order.
// Total error vs exact ~1e-7 => diff vs np-ref ~= np's own fp32 noise.

#define BETA 0.95f

static constexpr int B_ = 128;
static constexpr int T_ = 64;
static constexpr int M_ = B_ * T_;       // 8192 rows
static constexpr int NOUT = 128;

typedef __bf16 bf16x8 __attribute__((ext_vector_type(8)));
typedef float f32x4 __attribute__((ext_vector_type(4)));

__device__ __forceinline__ ushort f32_bf16_rne(float f) {
  uint32_t u = __float_as_uint(f);
  uint32_t r = u + 0x7FFFu + ((u >> 16) & 1u);
  return (ushort)(r >> 16);
}
__device__ __forceinline__ float bf16_f32(ushort h) {
  return __uint_as_float(((uint32_t)h) << 16);
}

// ---------------------------------------------------------------------------
// fp32 -> 3 bf16 exact split, written at swizzled slot positions.
// Logical (row, k=kb*64+slot*8+i) stored at row*K + kb*64 + (slot^(row&7))*8+i.
// ---------------------------------------------------------------------------
__global__ __launch_bounds__(256) void split3_swz(
    const float* __restrict__ S, ushort* __restrict__ o1,
    ushort* __restrict__ o2, ushort* __restrict__ o3,
    int K, int nslots)
{
  int g = blockIdx.x * 256 + threadIdx.x;
  if (g >= nslots) return;
  int spr = K >> 3;
  int row = g / spr;
  int sl = g - row * spr;
  int kb = sl >> 3;
  int slot = sl & 7;
  int pslot = slot ^ (row & 7);
  const float* src = S + (size_t)row * K + (kb << 6) + (slot << 3);
  size_t dst = (size_t)row * K + (kb << 6) + (pslot << 3);
#pragma unroll
  for (int i = 0; i < 8; ++i) {
    float f = src[i];
    ushort h1 = f32_bf16_rne(f);
    float r = f - bf16_f32(h1);
    ushort h2 = f32_bf16_rne(r);
    float r2 = r - bf16_f32(h2);
    ushort h3 = f32_bf16_rne(r2);
    o1[dst + i] = h1;
    o2[dst + i] = h2;
    o3[dst + i] = h3;
  }
}

// ---------------------------------------------------------------------------
// Segmented MFMA GEMM: acc = sum_p A[ai[p]] @ B[bi[p]]^T  (ONE chained acc).
// accum==0: C = acc.   accum==1: C += acc (RMW; each block owns its tile).
// 128x128 tile, BK=64, 4 waves, 16x16x32 bf16 MFMA, global_load_lds w16,
// XOR-swizzled LDS via pre-swizzled operand layout.
// ---------------------------------------------------------------------------
__global__ __launch_bounds__(256) void gemm_seg(
    const ushort* __restrict__ A0, const ushort* __restrict__ A1,
    const ushort* __restrict__ A2,
    const ushort* __restrict__ B0, const ushort* __restrict__ B1,
    const ushort* __restrict__ B2,
    int P, int apack, int bpack, int K, int N, int accum,
    float* __restrict__ C)
{
  __shared__ ushort As[128 * 64];
  __shared__ ushort Bs[128 * 64];

  const int tid = threadIdx.x;
  const int lane = tid & 63;
  const int wid = tid >> 6;
  const int wr = wid >> 1, wc = wid & 1;
  const int lane15 = lane & 15;
  const int lhi = lane >> 4;
  const int rswz = lane15 & 7;
  const int lrow = lane >> 3, lslot = lane & 7;

  // bijective XCD-aware block swizzle (all grids are multiples of 8)
  int nwg = gridDim.x * gridDim.y;
  int bid = blockIdx.y * gridDim.x + blockIdx.x;
  int cpx = nwg >> 3;
  int sw = (bid & 7) * cpx + (bid >> 3);
  int bx = sw % gridDim.x, by = sw / gridDim.x;
  const int bm = by * 128, bn = bx * 128;

  f32x4 acc[4][4];
#pragma unroll
  for (int i = 0; i < 4; ++i)
#pragma unroll
    for (int j = 0; j < 4; ++j)
      acc[i][j] = (f32x4){0.f, 0.f, 0.f, 0.f};

  const bool isA = (wid < 2);
  ushort* lbase = isA ? As : Bs;
  const int rowbase0 = isA ? bm : bn;
  const int chunk0 = (wid & 1) * 8;

  for (int p = 0; p < P; ++p) {
    int ai = (apack >> (2 * p)) & 3;
    int bi = (bpack >> (2 * p)) & 3;
    const ushort* Ap = ai == 0 ? A0 : (ai == 1 ? A1 : A2);
    const ushort* Bp = bi == 0 ? B0 : (bi == 1 ? B1 : B2);
    const ushort* gsrc = isA ? Ap : Bp;
    for (int k0 = 0; k0 < K; k0 += 64) {
      __syncthreads();  // previous tile fully consumed
#pragma unroll
      for (int c = 0; c < 8; ++c) {
        int chunk = chunk0 + c;
        int row = chunk * 8 + lrow;
        const ushort* g = gsrc + (size_t)(rowbase0 + row) * K + k0 + (lslot << 3);
        __builtin_amdgcn_global_load_lds(
            (__attribute__((address_space(1))) void*)(g),
            (__attribute__((address_space(3))) void*)(lbase + chunk * 512),
            16, 0, 0);
      }
      __syncthreads();  // drains vmcnt before barrier
#pragma unroll
      for (int kk = 0; kk < 2; ++kk) {
        int sp = ((kk << 2) | lhi) ^ rswz;
        bf16x8 af[4], bg[4];
#pragma unroll
        for (int i = 0; i < 4; ++i)
          af[i] = *(const bf16x8*)(As + (wr * 64 + i * 16 + lane15) * 64 + sp * 8);
#pragma unroll
        for (int j = 0; j < 4; ++j)
          bg[j] = *(const bf16x8*)(Bs + (wc * 64 + j * 16 + lane15) * 64 + sp * 8);
#pragma unroll
        for (int i = 0; i < 4; ++i)
#pragma unroll
          for (int j = 0; j < 4; ++j)
            acc[i][j] = __builtin_amdgcn_mfma_f32_16x16x32_bf16(
                af[i], bg[j], acc[i][j], 0, 0, 0);
      }
    }
  }

  // epilogue: C/D layout col = lane&15, row = (lane>>4)*4 + reg
#pragma unroll
  for (int j = 0; j < 4; ++j) {
    int col = bn + wc * 64 + j * 16 + lane15;
#pragma unroll
    for (int i = 0; i < 4; ++i) {
      f32x4 v = acc[i][j];
      int r0 = bm + wr * 64 + i * 16 + lhi * 4;
      if (accum) {
#pragma unroll
        for (int r = 0; r < 4; ++r) {
          size_t idx = (size_t)(r0 + r) * N + col;
          C[idx] = C[idx] + v[r];
        }
      } else {
#pragma unroll
        for (int r = 0; r < 4; ++r)
          C[(size_t)(r0 + r) * N + col] = v[r];
      }
    }
  }
}

// ---------------------------------------------------------------------------
// LIF scan: cur = buf[idx] + bias[n] (single rounding, matches ref).
// Writes spikes as bf16 {0,1} in the swizzled layout (key = m&7).
// ---------------------------------------------------------------------------
__global__ __launch_bounds__(256) void lif_spk_swz(
    const float* __restrict__ cur, const float* __restrict__ bias,
    ushort* __restrict__ spk, int N, int total)
{
  int g = blockIdx.x * 256 + threadIdx.x;
  if (g >= total) return;
  int b = g / N, n = g - b * N;
  int nb = n >> 6;
  int slot = (n >> 3) & 7;
  int nlow = n & 7;
  float bv = bias[n];
  float mem = 0.f;
  for (int t = 0; t < T_; ++t) {
    int m = b * T_ + t;
    float c = __fadd_rn(cur[(size_t)m * N + n], bv);
    float reset = ((mem - 1.0f) > 0.0f) ? 1.0f : 0.0f;
    mem = __fmul_rn(BETA, mem);
    mem = __fadd_rn(mem, c);
    mem = __fadd_rn(mem, -reset);
    ushort sv = ((mem - 1.0f) > 0.0f) ? (ushort)0x3F80 : (ushort)0;
    spk[(size_t)m * N + (nb << 6) + (((slot ^ (m & 7)) << 3) + nlow)] = sv;
  }
}

// Final layer: emit spk3 and mem3 (fp32) into d_out.
__global__ __launch_bounds__(256) void lif_final(
    const float* __restrict__ cur_in, const float* __restrict__ bias,
    float* __restrict__ spk_out, float* __restrict__ mem_out, int N, int total)
{
  int g = blockIdx.x * 256 + threadIdx.x;
  if (g >= total) return;
  int b = g / N, n = g - b * N;
  size_t base = (size_t)b * T_ * N + n;
  float bv = bias[n];
  float mem = 0.f;
  for (int t = 0; t < T_; ++t) {
    size_t idx = base + (size_t)t * N;
    float c = __fadd_rn(cur_in[idx], bv);
    float reset = ((mem - 1.0f) > 0.0f) ? 1.0f : 0.0f;
    mem = __fmul_rn(BETA, mem);
    mem = __fadd_rn(mem, c);
    mem = __fadd_rn(mem, -reset);
    spk_out[idx] = ((mem - 1.0f) > 0.0f) ? 1.0f : 0.0f;
    mem_out[idx] = mem;
  }
}

extern "C" void kernel_launch(void* const* d_in, const int* in_sizes, int n_in,
                              void* d_out, int out_size, void* d_ws, size_t ws_size,
                              hipStream_t stream)
{
  const float* x  = (const float*)d_in[0];
  const float* W0 = (const float*)d_in[1];
  const float* b0 = (const float*)d_in[2];
  const float* W1 = (const float*)d_in[3];
  const float* b1 = (const float*)d_in[4];
  const float* W2 = (const float*)d_in[5];
  const float* b2 = (const float*)d_in[6];
  const float* W3 = (const float*)d_in[7];
  const float* b3 = (const float*)d_in[8];
  float* out = (float*)d_out;

  char* ws = (char*)d_ws;
  size_t off = 0;
  auto take = [&](size_t bytes) -> char* {
    char* p = ws + off;
    off += (bytes + 255) & ~(size_t)255;
    return p;
  };

  ushort* w0s[3], *w1s[3], *w2s[3], *w3s[3], *xs[3];
  for (int i = 0; i < 3; ++i) w0s[i] = (ushort*)take((size_t)2048 * 2048 * 2);
  for (int i = 0; i < 3; ++i) w1s[i] = (ushort*)take((size_t)2048 * 2048 * 2);
  for (int i = 0; i < 3; ++i) w2s[i] = (ushort*)take((size_t)1024 * 2048 * 2);
  for (int i = 0; i < 3; ++i) w3s[i] = (ushort*)take((size_t)128 * 1024 * 2);
  for (int i = 0; i < 3; ++i) xs[i]  = (ushort*)take((size_t)M_ * 2048 * 2);
  float* cur = (float*)take((size_t)M_ * 2048 * 4);
  // spike buffers alias the x-split region (dead after L0 GEMMs)
  ushort* s0 = xs[0];
  ushort* s1 = xs[1];
  ushort* s2 = xs[2];

  dim3 blk(256);

  // --- splits ---
  {
    int ns = 2048 * 2048 / 8;
    split3_swz<<<(ns + 255) / 256, blk, 0, stream>>>(W0, w0s[0], w0s[1], w0s[2], 2048, ns);
    split3_swz<<<(ns + 255) / 256, blk, 0, stream>>>(W1, w1s[0], w1s[1], w1s[2], 2048, ns);
    ns = 1024 * 2048 / 8;
    split3_swz<<<(ns + 255) / 256, blk, 0, stream>>>(W2, w2s[0], w2s[1], w2s[2], 2048, ns);
    ns = 128 * 1024 / 8;
    split3_swz<<<(ns + 255) / 256, blk, 0, stream>>>(W3, w3s[0], w3s[1], w3s[2], 1024, ns);
    ns = M_ * 2048 / 8;
    split3_swz<<<(ns + 255) / 256, blk, 0, stream>>>(x, xs[0], xs[1], xs[2], 2048, ns);
  }

  // --- L0: main x1w1; corr chain x1w2,x2w1,x1w3,x2w2,x3w1 ---
  {
    dim3 grid(2048 / 128, M_ / 128);
    gemm_seg<<<grid, blk, 0, stream>>>(xs[0], xs[1], xs[2], w0s[0], w0s[1], w0s[2],
                                       1, 0, 0, 2048, 2048, 0, cur);
    int apack = 0 | (1 << 2) | (0 << 4) | (1 << 6) | (2 << 8);
    int bpack = 1 | (0 << 2) | (2 << 4) | (1 << 6) | (0 << 8);
    gemm_seg<<<grid, blk, 0, stream>>>(xs[0], xs[1], xs[2], w0s[0], w0s[1], w0s[2],
                                       5, apack, bpack, 2048, 2048, 1, cur);
    lif_spk_swz<<<(B_ * 2048) / 256, blk, 0, stream>>>(cur, b0, s0, 2048, B_ * 2048);
  }
  // --- L1: main s0@w1; corr s0@w2, s0@w3 ---
  {
    dim3 grid(2048 / 128, M_ / 128);
    gemm_seg<<<grid, blk, 0, stream>>>(s0, s0, s0, w1s[0], w1s[1], w1s[2],
                                       1, 0, 0, 2048, 2048, 0, cur);
    gemm_seg<<<grid, blk, 0, stream>>>(s0, s0, s0, w1s[0], w1s[1], w1s[2],
                                       2, 0, 1 | (2 << 2), 2048, 2048, 1, cur);
    lif_spk_swz<<<(B_ * 2048) / 256, blk, 0, stream>>>(cur, b1, s1, 2048, B_ * 2048);
  }
  // --- L2 ---
  {
    dim3 grid(1024 / 128, M_ / 128);
    gemm_seg<<<grid, blk, 0, stream>>>(s1, s1, s1, w2s[0], w2s[1], w2s[2],
                                       1, 0, 0, 2048, 1024, 0, cur);
    gemm_seg<<<grid, blk, 0, stream>>>(s1, s1, s1, w2s[0], w2s[1], w2s[2],
                                       2, 0, 1 | (2 << 2), 2048, 1024, 1, cur);
    lif_spk_swz<<<(B_ * 1024) / 256, blk, 0, stream>>>(cur, b2, s2, 1024, B_ * 1024);
  }
  // --- L3 + final LIF ---
  {
    dim3 grid(128 / 128, M_ / 128);
    gemm_seg<<<grid, blk, 0, stream>>>(s2, s2, s2, w3s[0], w3s[1], w3s[2],
                                       1, 0, 0, 1024, 128, 0, cur);
    gemm_seg<<<grid, blk, 0, stream>>>(s2, s2, s2, w3s[0], w3s[1], w3s[2],
                                       2, 0, 1 | (2 << 2), 1024, 128, 1, cur);
    float* spk3 = out;
    float* mem3 = out + (size_t)M_ * NOUT;
    lif_final<<<(B_ * NOUT) / 256, blk, 0, stream>>>(cur, b3, spk3, mem3, NOUT, B_ * NOUT);
  }
}

// Round 6
// 889.147 us; speedup vs baseline: 2.2432x; 1.1423x over previous
//
#include <hip/hip_runtime.h>
#include <cstddef>
#include <cstdint>

// SNN: 4x (Linear + LIF). GEMMs on bf16 MFMA via EXACT 3-term splitting with
// scale-segregated accumulation (identical math to R5 — same MFMA chain order).
// NEW: L0/L1 (N=2048) run on a 256x256-tile 8-wave pipelined kernel with
// counted s_waitcnt vmcnt(4) (loads stay in flight across barriers, T3+T4),
// k-half LDS double-buffer, 2-bit XOR pre-swizzle (conflict-free ds_read_b128),
// setprio around MFMA (T5), XCD block swizzle (T1). L2/L3 keep the R5 kernel.

#define BETA 0.95f

static constexpr int B_ = 128;
static constexpr int T_ = 64;
static constexpr int M_ = B_ * T_;       // 8192 rows
static constexpr int NOUT = 128;

typedef __bf16 bf16x8 __attribute__((ext_vector_type(8)));
typedef float f32x4 __attribute__((ext_vector_type(4)));

__device__ __forceinline__ ushort f32_bf16_rne(float f) {
  uint32_t u = __float_as_uint(f);
  uint32_t r = u + 0x7FFFu + ((u >> 16) & 1u);
  return (ushort)(r >> 16);
}
__device__ __forceinline__ float bf16_f32(ushort h) {
  return __uint_as_float(((uint32_t)h) << 16);
}

// ---------------------------------------------------------------------------
// fp32 -> 3 bf16 exact split, written at swizzled slot positions.
// mode 0 (128-tile kernel): stored slot = slot ^ (row&7)           [3-bit XOR]
// mode 1 (256-tile kernel): stored slot = (slot&4)|((slot&3)^((row>>1)&3))
//                           (XOR only within each 32-elem k-half)
// ---------------------------------------------------------------------------
__global__ __launch_bounds__(256) void split3_swz(
    const float* __restrict__ S, ushort* __restrict__ o1,
    ushort* __restrict__ o2, ushort* __restrict__ o3,
    int K, int nslots, int mode)
{
  int g = blockIdx.x * 256 + threadIdx.x;
  if (g >= nslots) return;
  int spr = K >> 3;
  int row = g / spr;
  int sl = g - row * spr;
  int kb = sl >> 3;
  int slot = sl & 7;
  int pslot = mode ? ((slot & 4) | ((slot & 3) ^ ((row >> 1) & 3)))
                   : (slot ^ (row & 7));
  const float* src = S + (size_t)row * K + (kb << 6) + (slot << 3);
  size_t dst = (size_t)row * K + (kb << 6) + (pslot << 3);
#pragma unroll
  for (int i = 0; i < 8; ++i) {
    float f = src[i];
    ushort h1 = f32_bf16_rne(f);
    float r = f - bf16_f32(h1);
    ushort h2 = f32_bf16_rne(r);
    float r2 = r - bf16_f32(h2);
    ushort h3 = f32_bf16_rne(r2);
    o1[dst + i] = h1;
    o2[dst + i] = h2;
    o3[dst + i] = h3;
  }
}

// ---------------------------------------------------------------------------
// R5 kernel (kept for L2/L3): 128x128 tile, BK=64, 4 waves, 2-barrier K-step.
// Operands use mode-0 (3-bit) swizzle.
// ---------------------------------------------------------------------------
__global__ __launch_bounds__(256) void gemm_seg(
    const ushort* __restrict__ A0, const ushort* __restrict__ A1,
    const ushort* __restrict__ A2,
    const ushort* __restrict__ B0, const ushort* __restrict__ B1,
    const ushort* __restrict__ B2,
    int P, int apack, int bpack, int K, int N, int accum,
    float* __restrict__ C)
{
  __shared__ ushort As[128 * 64];
  __shared__ ushort Bs[128 * 64];

  const int tid = threadIdx.x;
  const int lane = tid & 63;
  const int wid = tid >> 6;
  const int wr = wid >> 1, wc = wid & 1;
  const int lane15 = lane & 15;
  const int lhi = lane >> 4;
  const int rswz = lane15 & 7;
  const int lrow = lane >> 3, lslot = lane & 7;

  int nwg = gridDim.x * gridDim.y;
  int bid = blockIdx.y * gridDim.x + blockIdx.x;
  int cpx = nwg >> 3;
  int sw = (bid & 7) * cpx + (bid >> 3);
  int bx = sw % gridDim.x, by = sw / gridDim.x;
  const int bm = by * 128, bn = bx * 128;

  f32x4 acc[4][4];
#pragma unroll
  for (int i = 0; i < 4; ++i)
#pragma unroll
    for (int j = 0; j < 4; ++j)
      acc[i][j] = (f32x4){0.f, 0.f, 0.f, 0.f};

  const bool isA = (wid < 2);
  ushort* lbase = isA ? As : Bs;
  const int rowbase0 = isA ? bm : bn;
  const int chunk0 = (wid & 1) * 8;

  for (int p = 0; p < P; ++p) {
    int ai = (apack >> (2 * p)) & 3;
    int bi = (bpack >> (2 * p)) & 3;
    const ushort* Ap = ai == 0 ? A0 : (ai == 1 ? A1 : A2);
    const ushort* Bp = bi == 0 ? B0 : (bi == 1 ? B1 : B2);
    const ushort* gsrc = isA ? Ap : Bp;
    for (int k0 = 0; k0 < K; k0 += 64) {
      __syncthreads();
#pragma unroll
      for (int c = 0; c < 8; ++c) {
        int chunk = chunk0 + c;
        int row = chunk * 8 + lrow;
        const ushort* g = gsrc + (size_t)(rowbase0 + row) * K + k0 + (lslot << 3);
        __builtin_amdgcn_global_load_lds(
            (const __attribute__((address_space(1))) void*)(g),
            (__attribute__((address_space(3))) void*)(lbase + chunk * 512),
            16, 0, 0);
      }
      __syncthreads();
#pragma unroll
      for (int kk = 0; kk < 2; ++kk) {
        int sp = ((kk << 2) | lhi) ^ rswz;
        bf16x8 af[4], bg[4];
#pragma unroll
        for (int i = 0; i < 4; ++i)
          af[i] = *(const bf16x8*)(As + (wr * 64 + i * 16 + lane15) * 64 + sp * 8);
#pragma unroll
        for (int j = 0; j < 4; ++j)
          bg[j] = *(const bf16x8*)(Bs + (wc * 64 + j * 16 + lane15) * 64 + sp * 8);
#pragma unroll
        for (int i = 0; i < 4; ++i)
#pragma unroll
          for (int j = 0; j < 4; ++j)
            acc[i][j] = __builtin_amdgcn_mfma_f32_16x16x32_bf16(
                af[i], bg[j], acc[i][j], 0, 0, 0);
      }
    }
  }

#pragma unroll
  for (int j = 0; j < 4; ++j) {
    int col = bn + wc * 64 + j * 16 + lane15;
#pragma unroll
    for (int i = 0; i < 4; ++i) {
      f32x4 v = acc[i][j];
      int r0 = bm + wr * 64 + i * 16 + lhi * 4;
      if (accum) {
#pragma unroll
        for (int r = 0; r < 4; ++r) {
          size_t idx = (size_t)(r0 + r) * N + col;
          C[idx] = C[idx] + v[r];
        }
      } else {
#pragma unroll
        for (int r = 0; r < 4; ++r)
          C[(size_t)(r0 + r) * N + col] = v[r];
      }
    }
  }
}

// ---------------------------------------------------------------------------
// NEW: 256x256 tile, 8 waves (2Mx4N), K=2048 fixed, P chained passes.
// LDS per operand: [2 dbuf][2 khalf][256 rows][32 k] bf16 (64KB); A+B = 128KB.
// Pipeline: per phase (kk half) stage next tile's matching k-half pair
// (4 global_load_lds), then s_waitcnt vmcnt(4) + raw s_barrier — 4 loads
// always in flight across barriers (counted vmcnt, T4). Operands use mode-1
// (2-bit within-khalf) pre-swizzle; read granule = lhi ^ ((row>>1)&3).
// MFMA accumulation order identical to gemm_seg (same numerics).
// ---------------------------------------------------------------------------
__global__ __launch_bounds__(512, 2) void gemm256(
    const ushort* __restrict__ A0, const ushort* __restrict__ A1,
    const ushort* __restrict__ A2,
    const ushort* __restrict__ B0, const ushort* __restrict__ B1,
    const ushort* __restrict__ B2,
    int P, int apack, int bpack, int N, int accum,
    float* __restrict__ C)
{
  __shared__ __align__(16) ushort lds[65536];  // A: [0,32768), B: [32768,65536)

  const int tid = threadIdx.x;
  const int lane = tid & 63;
  const int wid = tid >> 6;        // 0..7
  const int wm = wid >> 2;         // 0..1  (M half)
  const int wn = wid & 3;          // 0..3  (N quarter)
  const int lane15 = lane & 15;
  const int lhi = lane >> 4;       // 0..3
  const int s2 = lhi ^ ((lane15 >> 1) & 3);  // stored granule within k-half

  // bijective XCD swizzle (grids are multiples of 8)
  int nwg = gridDim.x * gridDim.y;
  int bid = blockIdx.y * gridDim.x + blockIdx.x;
  int cpx = nwg >> 3;
  int sw = (bid & 7) * cpx + (bid >> 3);
  int bx = sw % gridDim.x, by = sw / gridDim.x;
  const int bm = by * 256, bn = bx * 256;

  // staging coords: 1024 slots of 16B per k-half pair side; thread does 2 (A) + 2 (B)
  const int r0s = tid >> 2;        // rows 0..127
  const int ks = tid & 3;          // 16B column within 64B row
  const int r1s = r0s + 128;       // rows 128..255

  auto stage_half = [&](const ushort* Ap, const ushort* Bp, int k0, int h, int d) {
    const int goff = k0 + h * 32 + ks * 8;
    const int loff = d * 16384 + h * 8192 + ks * 8;
    __builtin_amdgcn_global_load_lds(
        (const __attribute__((address_space(1))) void*)(Ap + (size_t)(bm + r0s) * 2048 + goff),
        (__attribute__((address_space(3))) void*)(lds + loff + r0s * 32), 16, 0, 0);
    __builtin_amdgcn_global_load_lds(
        (const __attribute__((address_space(1))) void*)(Ap + (size_t)(bm + r1s) * 2048 + goff),
        (__attribute__((address_space(3))) void*)(lds + loff + r1s * 32), 16, 0, 0);
    __builtin_amdgcn_global_load_lds(
        (const __attribute__((address_space(1))) void*)(Bp + (size_t)(bn + r0s) * 2048 + goff),
        (__attribute__((address_space(3))) void*)(lds + 32768 + loff + r0s * 32), 16, 0, 0);
    __builtin_amdgcn_global_load_lds(
        (const __attribute__((address_space(1))) void*)(Bp + (size_t)(bn + r1s) * 2048 + goff),
        (__attribute__((address_space(3))) void*)(lds + 32768 + loff + r1s * 32), 16, 0, 0);
  };

  f32x4 acc[8][4];
#pragma unroll
  for (int i = 0; i < 8; ++i)
#pragma unroll
    for (int j = 0; j < 4; ++j)
      acc[i][j] = (f32x4){0.f, 0.f, 0.f, 0.f};

  const int NT = P * 32;   // K=2048 -> 32 k-tiles per pass

  // prologue: stage both k-halves of tile 0; confirm half 0
  {
    int ai = apack & 3, bi = bpack & 3;
    const ushort* Ap = ai == 0 ? A0 : (ai == 1 ? A1 : A2);
    const ushort* Bp = bi == 0 ? B0 : (bi == 1 ? B1 : B2);
    stage_half(Ap, Bp, 0, 0, 0);
    stage_half(Ap, Bp, 0, 1, 0);
  }
  asm volatile("s_waitcnt vmcnt(4)" ::: "memory");
  asm volatile("s_barrier" ::: "memory");

  for (int kt = 0; kt < NT; ++kt) {
    const int d = kt & 1;
    const bool last = (kt == NT - 1);
    const int tn = kt + 1;
    const ushort* An = A0;
    const ushort* Bn = B0;
    if (!last) {
      int pn = tn >> 5;
      int ai = (apack >> (2 * pn)) & 3;
      int bi = (bpack >> (2 * pn)) & 3;
      An = ai == 0 ? A0 : (ai == 1 ? A1 : A2);
      Bn = bi == 0 ? B0 : (bi == 1 ? B1 : B2);
    }
    const int k0n = (tn & 31) * 64;

#pragma unroll
    for (int kk = 0; kk < 2; ++kk) {
      // fragment reads for this k-half (data confirmed at previous boundary)
      bf16x8 af[8], bf[4];
      const ushort* Ab = lds + d * 16384 + kk * 8192 + wm * 4096 + lane15 * 32 + s2 * 8;
#pragma unroll
      for (int i = 0; i < 8; ++i) af[i] = *(const bf16x8*)(Ab + i * 512);
      const ushort* Bb = lds + 32768 + d * 16384 + kk * 8192 + wn * 2048 + lane15 * 32 + s2 * 8;
#pragma unroll
      for (int j = 0; j < 4; ++j) bf[j] = *(const bf16x8*)(Bb + j * 512);

      if (!last) {
        stage_half(An, Bn, k0n, kk, d ^ 1);                  // next tile, same k-half
        asm volatile("s_waitcnt vmcnt(4)" ::: "memory");     // counted: 4 loads stay in flight
      } else if (kk == 0) {
        asm volatile("s_waitcnt vmcnt(0)" ::: "memory");     // final tile: drain
      }
      asm volatile("s_barrier" ::: "memory");

      __builtin_amdgcn_s_setprio(1);
#pragma unroll
      for (int i = 0; i < 8; ++i)
#pragma unroll
        for (int j = 0; j < 4; ++j)
          acc[i][j] = __builtin_amdgcn_mfma_f32_16x16x32_bf16(af[i], bf[j], acc[i][j], 0, 0, 0);
      __builtin_amdgcn_s_setprio(0);
      asm volatile("s_barrier" ::: "memory");
    }
  }

  // epilogue: C/D layout col = lane&15, row = (lane>>4)*4 + reg
#pragma unroll
  for (int i = 0; i < 8; ++i) {
    int r0 = bm + wm * 128 + i * 16 + lhi * 4;
#pragma unroll
    for (int j = 0; j < 4; ++j) {
      int col = bn + wn * 64 + j * 16 + lane15;
      f32x4 v = acc[i][j];
      if (accum) {
#pragma unroll
        for (int r = 0; r < 4; ++r) {
          size_t idx = (size_t)(r0 + r) * N + col;
          C[idx] = C[idx] + v[r];
        }
      } else {
#pragma unroll
        for (int r = 0; r < 4; ++r)
          C[(size_t)(r0 + r) * N + col] = v[r];
      }
    }
  }
}

// ---------------------------------------------------------------------------
// LIF scan: cur = buf[idx] + bias[n] (single rounding). Writes spikes as bf16
// {0,1} in the swizzled layout; mode selects the pre-swizzle variant.
// ---------------------------------------------------------------------------
__global__ __launch_bounds__(256) void lif_spk_swz(
    const float* __restrict__ cur, const float* __restrict__ bias,
    ushort* __restrict__ spk, int N, int total, int mode)
{
  int g = blockIdx.x * 256 + threadIdx.x;
  if (g >= total) return;
  int b = g / N, n = g - b * N;
  int nb = n >> 6;
  int slot = (n >> 3) & 7;
  int nlow = n & 7;
  float bv = bias[n];
  float mem = 0.f;
  for (int t = 0; t < T_; ++t) {
    int m = b * T_ + t;
    float c = __fadd_rn(cur[(size_t)m * N + n], bv);
    float reset = ((mem - 1.0f) > 0.0f) ? 1.0f : 0.0f;
    mem = __fmul_rn(BETA, mem);
    mem = __fadd_rn(mem, c);
    mem = __fadd_rn(mem, -reset);
    ushort sv = ((mem - 1.0f) > 0.0f) ? (ushort)0x3F80 : (ushort)0;
    int ps = mode ? ((slot & 4) | ((slot & 3) ^ ((m >> 1) & 3)))
                  : (slot ^ (m & 7));
    spk[(size_t)m * N + (nb << 6) + (ps << 3) + nlow] = sv;
  }
}

__global__ __launch_bounds__(256) void lif_final(
    const float* __restrict__ cur_in, const float* __restrict__ bias,
    float* __restrict__ spk_out, float* __restrict__ mem_out, int N, int total)
{
  int g = blockIdx.x * 256 + threadIdx.x;
  if (g >= total) return;
  int b = g / N, n = g - b * N;
  size_t base = (size_t)b * T_ * N + n;
  float bv = bias[n];
  float mem = 0.f;
  for (int t = 0; t < T_; ++t) {
    size_t idx = base + (size_t)t * N;
    float c = __fadd_rn(cur_in[idx], bv);
    float reset = ((mem - 1.0f) > 0.0f) ? 1.0f : 0.0f;
    mem = __fmul_rn(BETA, mem);
    mem = __fadd_rn(mem, c);
    mem = __fadd_rn(mem, -reset);
    spk_out[idx] = ((mem - 1.0f) > 0.0f) ? 1.0f : 0.0f;
    mem_out[idx] = mem;
  }
}

extern "C" void kernel_launch(void* const* d_in, const int* in_sizes, int n_in,
                              void* d_out, int out_size, void* d_ws, size_t ws_size,
                              hipStream_t stream)
{
  const float* x  = (const float*)d_in[0];
  const float* W0 = (const float*)d_in[1];
  const float* b0 = (const float*)d_in[2];
  const float* W1 = (const float*)d_in[3];
  const float* b1 = (const float*)d_in[4];
  const float* W2 = (const float*)d_in[5];
  const float* b2 = (const float*)d_in[6];
  const float* W3 = (const float*)d_in[7];
  const float* b3 = (const float*)d_in[8];
  float* out = (float*)d_out;

  char* ws = (char*)d_ws;
  size_t off = 0;
  auto take = [&](size_t bytes) -> char* {
    char* p = ws + off;
    off += (bytes + 255) & ~(size_t)255;
    return p;
  };

  ushort* w0s[3], *w1s[3], *w2s[3], *w3s[3], *xs[3];
  for (int i = 0; i < 3; ++i) w0s[i] = (ushort*)take((size_t)2048 * 2048 * 2);
  for (int i = 0; i < 3; ++i) w1s[i] = (ushort*)take((size_t)2048 * 2048 * 2);
  for (int i = 0; i < 3; ++i) w2s[i] = (ushort*)take((size_t)1024 * 2048 * 2);
  for (int i = 0; i < 3; ++i) w3s[i] = (ushort*)take((size_t)128 * 1024 * 2);
  for (int i = 0; i < 3; ++i) xs[i]  = (ushort*)take((size_t)M_ * 2048 * 2);
  float* cur = (float*)take((size_t)M_ * 2048 * 4);
  // spike buffers alias the x-split region (dead after L0 GEMMs)
  ushort* s0 = xs[0];
  ushort* s1 = xs[1];
  ushort* s2 = xs[2];

  dim3 blk(256);

  // --- splits: mode 1 (256-kernel operands): x, W0, W1; mode 0: W2, W3 ---
  {
    int ns = 2048 * 2048 / 8;
    split3_swz<<<(ns + 255) / 256, blk, 0, stream>>>(W0, w0s[0], w0s[1], w0s[2], 2048, ns, 1);
    split3_swz<<<(ns + 255) / 256, blk, 0, stream>>>(W1, w1s[0], w1s[1], w1s[2], 2048, ns, 1);
    ns = 1024 * 2048 / 8;
    split3_swz<<<(ns + 255) / 256, blk, 0, stream>>>(W2, w2s[0], w2s[1], w2s[2], 2048, ns, 0);
    ns = 128 * 1024 / 8;
    split3_swz<<<(ns + 255) / 256, blk, 0, stream>>>(W3, w3s[0], w3s[1], w3s[2], 1024, ns, 0);
    ns = M_ * 2048 / 8;
    split3_swz<<<(ns + 255) / 256, blk, 0, stream>>>(x, xs[0], xs[1], xs[2], 2048, ns, 1);
  }

  // --- L0 (gemm256): main x1w1; corr chain x1w2,x2w1,x1w3,x2w2,x3w1 ---
  {
    dim3 grid(2048 / 256, M_ / 256);  // (8, 32)
    gemm256<<<grid, dim3(512), 0, stream>>>(xs[0], xs[1], xs[2], w0s[0], w0s[1], w0s[2],
                                            1, 0, 0, 2048, 0, cur);
    int apack = 0 | (1 << 2) | (0 << 4) | (1 << 6) | (2 << 8);
    int bpack = 1 | (0 << 2) | (2 << 4) | (1 << 6) | (0 << 8);
    gemm256<<<grid, dim3(512), 0, stream>>>(xs[0], xs[1], xs[2], w0s[0], w0s[1], w0s[2],
                                            5, apack, bpack, 2048, 1, cur);
    lif_spk_swz<<<(B_ * 2048) / 256, blk, 0, stream>>>(cur, b0, s0, 2048, B_ * 2048, 1);
  }
  // --- L1 (gemm256): main s0@w1; corr s0@w2, s0@w3 ---
  {
    dim3 grid(2048 / 256, M_ / 256);
    gemm256<<<grid, dim3(512), 0, stream>>>(s0, s0, s0, w1s[0], w1s[1], w1s[2],
                                            1, 0, 0, 2048, 0, cur);
    gemm256<<<grid, dim3(512), 0, stream>>>(s0, s0, s0, w1s[0], w1s[1], w1s[2],
                                            2, 0, 1 | (2 << 2), 2048, 1, cur);
    lif_spk_swz<<<(B_ * 2048) / 256, blk, 0, stream>>>(cur, b1, s1, 2048, B_ * 2048, 0);
  }
  // --- L2 (gemm_seg, mode-0 operands) ---
  {
    dim3 grid(1024 / 128, M_ / 128);
    gemm_seg<<<grid, blk, 0, stream>>>(s1, s1, s1, w2s[0], w2s[1], w2s[2],
                                       1, 0, 0, 2048, 1024, 0, cur);
    gemm_seg<<<grid, blk, 0, stream>>>(s1, s1, s1, w2s[0], w2s[1], w2s[2],
                                       2, 0, 1 | (2 << 2), 2048, 1024, 1, cur);
    lif_spk_swz<<<(B_ * 1024) / 256, blk, 0, stream>>>(cur, b2, s2, 1024, B_ * 1024, 0);
  }
  // --- L3 (gemm_seg) + final LIF ---
  {
    dim3 grid(128 / 128, M_ / 128);
    gemm_seg<<<grid, blk, 0, stream>>>(s2, s2, s2, w3s[0], w3s[1], w3s[2],
                                       1, 0, 0, 1024, 128, 0, cur);
    gemm_seg<<<grid, blk, 0, stream>>>(s2, s2, s2, w3s[0], w3s[1], w3s[2],
                                       2, 0, 1 | (2 << 2), 1024, 128, 1, cur);
    float* spk3 = out;
    float* mem3 = out + (size_t)M_ * NOUT;
    lif_final<<<(B_ * NOUT) / 256, blk, 0, stream>>>(cur, b3, spk3, mem3, NOUT, B_ * NOUT);
  }
}

// Round 7
// 875.914 us; speedup vs baseline: 2.2771x; 1.0151x over previous
//
#include <hip/hip_runtime.h>
#include <cstddef>
#include <cstdint>

// SNN: 4x (Linear + LIF). GEMMs on bf16 MFMA via EXACT 3-term splitting with
// scale-segregated accumulation (same MFMA chain order as R5/R6 -> identical
// numerics). gemm256 (L0/L1, N=2048): 256x256 tile, 8 waves, 4-phase K-tile
// schedule (16-MFMA clusters, per-phase ds_read + 2-load staging, counted
// vmcnt(4) twice per K-tile, setprio around MFMA), XCD swizzle, pre-swizzled
// operands (conflict-free ds_read_b128). L2/L3 keep the 128-tile gemm_seg.

#define BETA 0.95f

static constexpr int B_ = 128;
static constexpr int T_ = 64;
static constexpr int M_ = B_ * T_;       // 8192 rows
static constexpr int NOUT = 128;

typedef __bf16 bf16x8 __attribute__((ext_vector_type(8)));
typedef float f32x4 __attribute__((ext_vector_type(4)));
typedef ushort u16x8 __attribute__((ext_vector_type(8)));

__device__ __forceinline__ ushort f32_bf16_rne(float f) {
  uint32_t u = __float_as_uint(f);
  uint32_t r = u + 0x7FFFu + ((u >> 16) & 1u);
  return (ushort)(r >> 16);
}
__device__ __forceinline__ float bf16_f32(ushort h) {
  return __uint_as_float(((uint32_t)h) << 16);
}

// ---------------------------------------------------------------------------
// fp32 -> 3 bf16 exact split, written at swizzled slot positions.
// mode 0 (128-tile kernel): stored slot = slot ^ (row&7)           [3-bit XOR]
// mode 1 (256-tile kernel): stored slot = (slot&4)|((slot&3)^((row>>1)&3))
// ---------------------------------------------------------------------------
__global__ __launch_bounds__(256) void split3_swz(
    const float* __restrict__ S, ushort* __restrict__ o1,
    ushort* __restrict__ o2, ushort* __restrict__ o3,
    int K, int nslots, int mode)
{
  int g = blockIdx.x * 256 + threadIdx.x;
  if (g >= nslots) return;
  int spr = K >> 3;
  int row = g / spr;
  int sl = g - row * spr;
  int kb = sl >> 3;
  int slot = sl & 7;
  int pslot = mode ? ((slot & 4) | ((slot & 3) ^ ((row >> 1) & 3)))
                   : (slot ^ (row & 7));
  const float* src = S + (size_t)row * K + (kb << 6) + (slot << 3);
  size_t dst = (size_t)row * K + (kb << 6) + (pslot << 3);
  u16x8 v1, v2, v3;
#pragma unroll
  for (int i = 0; i < 8; ++i) {
    float f = src[i];
    ushort h1 = f32_bf16_rne(f);
    float r = f - bf16_f32(h1);
    ushort h2 = f32_bf16_rne(r);
    float r2 = r - bf16_f32(h2);
    ushort h3 = f32_bf16_rne(r2);
    v1[i] = h1; v2[i] = h2; v3[i] = h3;
  }
  *reinterpret_cast<u16x8*>(o1 + dst) = v1;
  *reinterpret_cast<u16x8*>(o2 + dst) = v2;
  *reinterpret_cast<u16x8*>(o3 + dst) = v3;
}

// ---------------------------------------------------------------------------
// R5 kernel (kept for L2/L3): 128x128 tile, BK=64, 4 waves, 2-barrier K-step.
// Operands use mode-0 (3-bit) swizzle.
// ---------------------------------------------------------------------------
__global__ __launch_bounds__(256) void gemm_seg(
    const ushort* __restrict__ A0, const ushort* __restrict__ A1,
    const ushort* __restrict__ A2,
    const ushort* __restrict__ B0, const ushort* __restrict__ B1,
    const ushort* __restrict__ B2,
    int P, int apack, int bpack, int K, int N, int accum,
    float* __restrict__ C)
{
  __shared__ ushort As[128 * 64];
  __shared__ ushort Bs[128 * 64];

  const int tid = threadIdx.x;
  const int lane = tid & 63;
  const int wid = tid >> 6;
  const int wr = wid >> 1, wc = wid & 1;
  const int lane15 = lane & 15;
  const int lhi = lane >> 4;
  const int rswz = lane15 & 7;
  const int lrow = lane >> 3, lslot = lane & 7;

  int nwg = gridDim.x * gridDim.y;
  int bid = blockIdx.y * gridDim.x + blockIdx.x;
  int cpx = nwg >> 3;
  int sw = (bid & 7) * cpx + (bid >> 3);
  int bx = sw % gridDim.x, by = sw / gridDim.x;
  const int bm = by * 128, bn = bx * 128;

  f32x4 acc[4][4];
#pragma unroll
  for (int i = 0; i < 4; ++i)
#pragma unroll
    for (int j = 0; j < 4; ++j)
      acc[i][j] = (f32x4){0.f, 0.f, 0.f, 0.f};

  const bool isA = (wid < 2);
  ushort* lbase = isA ? As : Bs;
  const int rowbase0 = isA ? bm : bn;
  const int chunk0 = (wid & 1) * 8;

  for (int p = 0; p < P; ++p) {
    int ai = (apack >> (2 * p)) & 3;
    int bi = (bpack >> (2 * p)) & 3;
    const ushort* Ap = ai == 0 ? A0 : (ai == 1 ? A1 : A2);
    const ushort* Bp = bi == 0 ? B0 : (bi == 1 ? B1 : B2);
    const ushort* gsrc = isA ? Ap : Bp;
    for (int k0 = 0; k0 < K; k0 += 64) {
      __syncthreads();
#pragma unroll
      for (int c = 0; c < 8; ++c) {
        int chunk = chunk0 + c;
        int row = chunk * 8 + lrow;
        const ushort* g = gsrc + (size_t)(rowbase0 + row) * K + k0 + (lslot << 3);
        __builtin_amdgcn_global_load_lds(
            (const __attribute__((address_space(1))) void*)(g),
            (__attribute__((address_space(3))) void*)(lbase + chunk * 512),
            16, 0, 0);
      }
      __syncthreads();
#pragma unroll
      for (int kk = 0; kk < 2; ++kk) {
        int sp = ((kk << 2) | lhi) ^ rswz;
        bf16x8 af[4], bg[4];
#pragma unroll
        for (int i = 0; i < 4; ++i)
          af[i] = *(const bf16x8*)(As + (wr * 64 + i * 16 + lane15) * 64 + sp * 8);
#pragma unroll
        for (int j = 0; j < 4; ++j)
          bg[j] = *(const bf16x8*)(Bs + (wc * 64 + j * 16 + lane15) * 64 + sp * 8);
#pragma unroll
        for (int i = 0; i < 4; ++i)
#pragma unroll
          for (int j = 0; j < 4; ++j)
            acc[i][j] = __builtin_amdgcn_mfma_f32_16x16x32_bf16(
                af[i], bg[j], acc[i][j], 0, 0, 0);
      }
    }
  }

#pragma unroll
  for (int j = 0; j < 4; ++j) {
    int col = bn + wc * 64 + j * 16 + lane15;
#pragma unroll
    for (int i = 0; i < 4; ++i) {
      f32x4 v = acc[i][j];
      int r0 = bm + wr * 64 + i * 16 + lhi * 4;
      if (accum) {
#pragma unroll
        for (int r = 0; r < 4; ++r) {
          size_t idx = (size_t)(r0 + r) * N + col;
          C[idx] = C[idx] + v[r];
        }
      } else {
#pragma unroll
        for (int r = 0; r < 4; ++r)
          C[(size_t)(r0 + r) * N + col] = v[r];
      }
    }
  }
}

// ---------------------------------------------------------------------------
// gemm256 v2: 256x256 tile, 8 waves (2Mx4N), K=2048, P chained passes.
// LDS per operand: [2 dbuf][2 khalf][256 rows][32 k] bf16; A+B = 128KB.
// 4 phases per K-tile: (h0,i0-3),(h0,i4-7),(h1,i0-3),(h1,i4-7). Each phase:
// {4-8 ds_read_b128; 2 global_load_lds staging; barrier; 16 MFMA in
// setprio(1)}. Counted s_waitcnt vmcnt(4) only at phases 1 and 3:
//   at ph1 wait: outstanding = prev-tile h1 (4, oldest) + this ph0/ph1 (4)
//     -> vmcnt(4) confirms prev h1 before ph2 reads it.
//   at ph3 wait: outstanding = this tile's 8 -> vmcnt(4) confirms next-buf h0
//     before next tile's ph0 reads it.
// Per-acc MFMA chain order (pass -> k0 asc -> h0,h1) identical to gemm_seg.
// ---------------------------------------------------------------------------
__global__ __launch_bounds__(512, 2) void gemm256(
    const ushort* __restrict__ A0, const ushort* __restrict__ A1,
    const ushort* __restrict__ A2,
    const ushort* __restrict__ B0, const ushort* __restrict__ B1,
    const ushort* __restrict__ B2,
    int P, int apack, int bpack, int N, int accum,
    float* __restrict__ C)
{
  __shared__ __align__(16) ushort lds[65536];  // A: [0,32768), B: [32768,65536)

  const int tid = threadIdx.x;
  const int lane = tid & 63;
  const int wid = tid >> 6;        // 0..7
  const int wm = wid >> 2;         // 0..1  (M half)
  const int wn = wid & 3;          // 0..3  (N quarter)
  const int lane15 = lane & 15;
  const int lhi = lane >> 4;       // 0..3
  const int s2 = lhi ^ ((lane15 >> 1) & 3);  // stored granule within k-half

  // bijective XCD swizzle (grids are multiples of 8)
  int nwg = gridDim.x * gridDim.y;
  int bid = blockIdx.y * gridDim.x + blockIdx.x;
  int cpx = nwg >> 3;
  int sw = (bid & 7) * cpx + (bid >> 3);
  int bx = sw % gridDim.x, by = sw / gridDim.x;
  const int bm = by * 256, bn = bx * 256;

  // staging coords: per wave 2 loads per quarter (rows tid>>2 and +128)
  const int r0s = tid >> 2;        // rows 0..127
  const int ks = tid & 3;          // 16B column within 64B row
  const int r1s = r0s + 128;       // rows 128..255

  auto stageA = [&](const ushort* Ap, int k0, int h, int d) {
    const int goff = k0 + h * 32 + ks * 8;
    const int loff = d * 16384 + h * 8192 + ks * 8;
    __builtin_amdgcn_global_load_lds(
        (const __attribute__((address_space(1))) void*)(Ap + (size_t)(bm + r0s) * 2048 + goff),
        (__attribute__((address_space(3))) void*)(lds + loff + r0s * 32), 16, 0, 0);
    __builtin_amdgcn_global_load_lds(
        (const __attribute__((address_space(1))) void*)(Ap + (size_t)(bm + r1s) * 2048 + goff),
        (__attribute__((address_space(3))) void*)(lds + loff + r1s * 32), 16, 0, 0);
  };
  auto stageB = [&](const ushort* Bp, int k0, int h, int d) {
    const int goff = k0 + h * 32 + ks * 8;
    const int loff = 32768 + d * 16384 + h * 8192 + ks * 8;
    __builtin_amdgcn_global_load_lds(
        (const __attribute__((address_space(1))) void*)(Bp + (size_t)(bn + r0s) * 2048 + goff),
        (__attribute__((address_space(3))) void*)(lds + loff + r0s * 32), 16, 0, 0);
    __builtin_amdgcn_global_load_lds(
        (const __attribute__((address_space(1))) void*)(Bp + (size_t)(bn + r1s) * 2048 + goff),
        (__attribute__((address_space(3))) void*)(lds + loff + r1s * 32), 16, 0, 0);
  };

  f32x4 acc[8][4];
#pragma unroll
  for (int i = 0; i < 8; ++i)
#pragma unroll
    for (int j = 0; j < 4; ++j)
      acc[i][j] = (f32x4){0.f, 0.f, 0.f, 0.f};

  const int NT = P * 32;   // K=2048 -> 32 k-tiles per pass

  // prologue: stage both k-halves of tile 0 into buf 0 (order h0 A,B then h1)
  {
    int ai = apack & 3, bi = bpack & 3;
    const ushort* Ap = ai == 0 ? A0 : (ai == 1 ? A1 : A2);
    const ushort* Bp = bi == 0 ? B0 : (bi == 1 ? B1 : B2);
    stageA(Ap, 0, 0, 0);
    stageB(Bp, 0, 0, 0);
    stageA(Ap, 0, 1, 0);
    stageB(Bp, 0, 1, 0);
  }
  asm volatile("s_waitcnt vmcnt(4)" ::: "memory");  // h0 landed; h1 in flight
  asm volatile("s_barrier" ::: "memory");

  const int aoff = wm * 128 * 32 + lane15 * 32 + s2 * 8;   // + i*512 (+64*32 for iB)
  const int boff = wn * 64 * 32 + lane15 * 32 + s2 * 8;    // + j*512

  for (int kt = 0; kt < NT; ++kt) {
    const int d = kt & 1;
    const int dn = d ^ 1;
    const bool last = (kt == NT - 1);
    const ushort* An = A0;
    const ushort* Bn = B0;
    int k0n = 0;
    if (!last) {
      int tn = kt + 1;
      int pn = tn >> 5;
      int ai = (apack >> (2 * pn)) & 3;
      int bi = (bpack >> (2 * pn)) & 3;
      An = ai == 0 ? A0 : (ai == 1 ? A1 : A2);
      Bn = bi == 0 ? B0 : (bi == 1 ? B1 : B2);
      k0n = (tn & 31) * 64;
    }
    const ushort* Ab = lds + d * 16384;
    const ushort* Bb = lds + 32768 + d * 16384;

    bf16x8 aa[4], bb[4];

    // ---- phase 0: h0, i0..3 (reads A-iA h0, B h0) ----
#pragma unroll
    for (int i = 0; i < 4; ++i) aa[i] = *(const bf16x8*)(Ab + aoff + i * 512);
#pragma unroll
    for (int j = 0; j < 4; ++j) bb[j] = *(const bf16x8*)(Bb + boff + j * 512);
    if (!last) stageA(An, k0n, 0, dn);
    asm volatile("s_barrier" ::: "memory");
    __builtin_amdgcn_s_setprio(1);
#pragma unroll
    for (int i = 0; i < 4; ++i)
#pragma unroll
      for (int j = 0; j < 4; ++j)
        acc[i][j] = __builtin_amdgcn_mfma_f32_16x16x32_bf16(aa[i], bb[j], acc[i][j], 0, 0, 0);
    __builtin_amdgcn_s_setprio(0);
    asm volatile("s_barrier" ::: "memory");

    // ---- phase 1: h0, i4..7 (reads A-iB h0; reuses B h0) ----
#pragma unroll
    for (int i = 0; i < 4; ++i) aa[i] = *(const bf16x8*)(Ab + aoff + 64 * 32 + i * 512);
    if (!last) {
      stageB(Bn, k0n, 0, dn);
      asm volatile("s_waitcnt vmcnt(4)" ::: "memory");  // prev-tile h1 landed
    } else {
      asm volatile("s_waitcnt vmcnt(0)" ::: "memory");  // final drain
    }
    asm volatile("s_barrier" ::: "memory");
    __builtin_amdgcn_s_setprio(1);
#pragma unroll
    for (int i = 0; i < 4; ++i)
#pragma unroll
      for (int j = 0; j < 4; ++j)
        acc[4 + i][j] = __builtin_amdgcn_mfma_f32_16x16x32_bf16(aa[i], bb[j], acc[4 + i][j], 0, 0, 0);
    __builtin_amdgcn_s_setprio(0);
    asm volatile("s_barrier" ::: "memory");

    // ---- phase 2: h1, i0..3 (reads A-iA h1, B h1) ----
#pragma unroll
    for (int i = 0; i < 4; ++i) aa[i] = *(const bf16x8*)(Ab + 8192 + aoff + i * 512);
#pragma unroll
    for (int j = 0; j < 4; ++j) bb[j] = *(const bf16x8*)(Bb + 8192 + boff + j * 512);
    if (!last) stageA(An, k0n, 1, dn);
    asm volatile("s_barrier" ::: "memory");
    __builtin_amdgcn_s_setprio(1);
#pragma unroll
    for (int i = 0; i < 4; ++i)
#pragma unroll
      for (int j = 0; j < 4; ++j)
        acc[i][j] = __builtin_amdgcn_mfma_f32_16x16x32_bf16(aa[i], bb[j], acc[i][j], 0, 0, 0);
    __builtin_amdgcn_s_setprio(0);
    asm volatile("s_barrier" ::: "memory");

    // ---- phase 3: h1, i4..7 (reads A-iB h1; reuses B h1) ----
#pragma unroll
    for (int i = 0; i < 4; ++i) aa[i] = *(const bf16x8*)(Ab + 8192 + aoff + 64 * 32 + i * 512);
    if (!last) {
      stageB(Bn, k0n, 1, dn);
      asm volatile("s_waitcnt vmcnt(4)" ::: "memory");  // next-buf h0 landed
    }
    asm volatile("s_barrier" ::: "memory");
    __builtin_amdgcn_s_setprio(1);
#pragma unroll
    for (int i = 0; i < 4; ++i)
#pragma unroll
      for (int j = 0; j < 4; ++j)
        acc[4 + i][j] = __builtin_amdgcn_mfma_f32_16x16x32_bf16(aa[i], bb[j], acc[4 + i][j], 0, 0, 0);
    __builtin_amdgcn_s_setprio(0);
    asm volatile("s_barrier" ::: "memory");
  }

  // epilogue: C/D layout col = lane&15, row = (lane>>4)*4 + reg
#pragma unroll
  for (int i = 0; i < 8; ++i) {
    int r0 = bm + wm * 128 + i * 16 + lhi * 4;
#pragma unroll
    for (int j = 0; j < 4; ++j) {
      int col = bn + wn * 64 + j * 16 + lane15;
      f32x4 v = acc[i][j];
      if (accum) {
#pragma unroll
        for (int r = 0; r < 4; ++r) {
          size_t idx = (size_t)(r0 + r) * N + col;
          C[idx] = C[idx] + v[r];
        }
      } else {
#pragma unroll
        for (int r = 0; r < 4; ++r)
          C[(size_t)(r0 + r) * N + col] = v[r];
      }
    }
  }
}

// ---------------------------------------------------------------------------
// LIF scan: cur = buf[idx] + bias[n] (single rounding). Writes spikes as bf16
// {0,1} in the swizzled layout; mode selects the pre-swizzle variant.
// ---------------------------------------------------------------------------
__global__ __launch_bounds__(256) void lif_spk_swz(
    const float* __restrict__ cur, const float* __restrict__ bias,
    ushort* __restrict__ spk, int N, int total, int mode)
{
  int g = blockIdx.x * 256 + threadIdx.x;
  if (g >= total) return;
  int b = g / N, n = g - b * N;
  int nb = n >> 6;
  int slot = (n >> 3) & 7;
  int nlow = n & 7;
  float bv = bias[n];
  float mem = 0.f;
  for (int t = 0; t < T_; ++t) {
    int m = b * T_ + t;
    float c = __fadd_rn(cur[(size_t)m * N + n], bv);
    float reset = ((mem - 1.0f) > 0.0f) ? 1.0f : 0.0f;
    mem = __fmul_rn(BETA, mem);
    mem = __fadd_rn(mem, c);
    mem = __fadd_rn(mem, -reset);
    ushort sv = ((mem - 1.0f) > 0.0f) ? (ushort)0x3F80 : (ushort)0;
    int ps = mode ? ((slot & 4) | ((slot & 3) ^ ((m >> 1) & 3)))
                  : (slot ^ (m & 7));
    spk[(size_t)m * N + (nb << 6) + (ps << 3) + nlow] = sv;
  }
}

__global__ __launch_bounds__(256) void lif_final(
    const float* __restrict__ cur_in, const float* __restrict__ bias,
    float* __restrict__ spk_out, float* __restrict__ mem_out, int N, int total)
{
  int g = blockIdx.x * 256 + threadIdx.x;
  if (g >= total) return;
  int b = g / N, n = g - b * N;
  size_t base = (size_t)b * T_ * N + n;
  float bv = bias[n];
  float mem = 0.f;
  for (int t = 0; t < T_; ++t) {
    size_t idx = base + (size_t)t * N;
    float c = __fadd_rn(cur_in[idx], bv);
    float reset = ((mem - 1.0f) > 0.0f) ? 1.0f : 0.0f;
    mem = __fmul_rn(BETA, mem);
    mem = __fadd_rn(mem, c);
    mem = __fadd_rn(mem, -reset);
    spk_out[idx] = ((mem - 1.0f) > 0.0f) ? 1.0f : 0.0f;
    mem_out[idx] = mem;
  }
}

extern "C" void kernel_launch(void* const* d_in, const int* in_sizes, int n_in,
                              void* d_out, int out_size, void* d_ws, size_t ws_size,
                              hipStream_t stream)
{
  const float* x  = (const float*)d_in[0];
  const float* W0 = (const float*)d_in[1];
  const float* b0 = (const float*)d_in[2];
  const float* W1 = (const float*)d_in[3];
  const float* b1 = (const float*)d_in[4];
  const float* W2 = (const float*)d_in[5];
  const float* b2 = (const float*)d_in[6];
  const float* W3 = (const float*)d_in[7];
  const float* b3 = (const float*)d_in[8];
  float* out = (float*)d_out;

  char* ws = (char*)d_ws;
  size_t off = 0;
  auto take = [&](size_t bytes) -> char* {
    char* p = ws + off;
    off += (bytes + 255) & ~(size_t)255;
    return p;
  };

  ushort* w0s[3], *w1s[3], *w2s[3], *w3s[3], *xs[3];
  for (int i = 0; i < 3; ++i) w0s[i] = (ushort*)take((size_t)2048 * 2048 * 2);
  for (int i = 0; i < 3; ++i) w1s[i] = (ushort*)take((size_t)2048 * 2048 * 2);
  for (int i = 0; i < 3; ++i) w2s[i] = (ushort*)take((size_t)1024 * 2048 * 2);
  for (int i = 0; i < 3; ++i) w3s[i] = (ushort*)take((size_t)128 * 1024 * 2);
  for (int i = 0; i < 3; ++i) xs[i]  = (ushort*)take((size_t)M_ * 2048 * 2);
  float* cur = (float*)take((size_t)M_ * 2048 * 4);
  // spike buffers alias the x-split region (dead after L0 GEMMs)
  ushort* s0 = xs[0];
  ushort* s1 = xs[1];
  ushort* s2 = xs[2];

  dim3 blk(256);

  // --- splits: mode 1 (gemm256 operands): x, W0, W1; mode 0: W2, W3 ---
  {
    int ns = 2048 * 2048 / 8;
    split3_swz<<<(ns + 255) / 256, blk, 0, stream>>>(W0, w0s[0], w0s[1], w0s[2], 2048, ns, 1);
    split3_swz<<<(ns + 255) / 256, blk, 0, stream>>>(W1, w1s[0], w1s[1], w1s[2], 2048, ns, 1);
    ns = 1024 * 2048 / 8;
    split3_swz<<<(ns + 255) / 256, blk, 0, stream>>>(W2, w2s[0], w2s[1], w2s[2], 2048, ns, 0);
    ns = 128 * 1024 / 8;
    split3_swz<<<(ns + 255) / 256, blk, 0, stream>>>(W3, w3s[0], w3s[1], w3s[2], 1024, ns, 0);
    ns = M_ * 2048 / 8;
    split3_swz<<<(ns + 255) / 256, blk, 0, stream>>>(x, xs[0], xs[1], xs[2], 2048, ns, 1);
  }

  // --- L0 (gemm256): main x1w1; corr chain x1w2,x2w1,x1w3,x2w2,x3w1 ---
  {
    dim3 grid(2048 / 256, M_ / 256);  // (8, 32)
    gemm256<<<grid, dim3(512), 0, stream>>>(xs[0], xs[1], xs[2], w0s[0], w0s[1], w0s[2],
                                            1, 0, 0, 2048, 0, cur);
    int apack = 0 | (1 << 2) | (0 << 4) | (1 << 6) | (2 << 8);
    int bpack = 1 | (0 << 2) | (2 << 4) | (1 << 6) | (0 << 8);
    gemm256<<<grid, dim3(512), 0, stream>>>(xs[0], xs[1], xs[2], w0s[0], w0s[1], w0s[2],
                                            5, apack, bpack, 2048, 1, cur);
    lif_spk_swz<<<(B_ * 2048) / 256, blk, 0, stream>>>(cur, b0, s0, 2048, B_ * 2048, 1);
  }
  // --- L1 (gemm256): main s0@w1; corr s0@w2, s0@w3 ---
  {
    dim3 grid(2048 / 256, M_ / 256);
    gemm256<<<grid, dim3(512), 0, stream>>>(s0, s0, s0, w1s[0], w1s[1], w1s[2],
                                            1, 0, 0, 2048, 0, cur);
    gemm256<<<grid, dim3(512), 0, stream>>>(s0, s0, s0, w1s[0], w1s[1], w1s[2],
                                            2, 0, 1 | (2 << 2), 2048, 1, cur);
    lif_spk_swz<<<(B_ * 2048) / 256, blk, 0, stream>>>(cur, b1, s1, 2048, B_ * 2048, 0);
  }
  // --- L2 (gemm_seg, mode-0 operands) ---
  {
    dim3 grid(1024 / 128, M_ / 128);
    gemm_seg<<<grid, blk, 0, stream>>>(s1, s1, s1, w2s[0], w2s[1], w2s[2],
                                       1, 0, 0, 2048, 1024, 0, cur);
    gemm_seg<<<grid, blk, 0, stream>>>(s1, s1, s1, w2s[0], w2s[1], w2s[2],
                                       2, 0, 1 | (2 << 2), 2048, 1024, 1, cur);
    lif_spk_swz<<<(B_ * 1024) / 256, blk, 0, stream>>>(cur, b2, s2, 1024, B_ * 1024, 0);
  }
  // --- L3 (gemm_seg) + final LIF ---
  {
    dim3 grid(128 / 128, M_ / 128);
    gemm_seg<<<grid, blk, 0, stream>>>(s2, s2, s2, w3s[0], w3s[1], w3s[2],
                                       1, 0, 0, 1024, 128, 0, cur);
    gemm_seg<<<grid, blk, 0, stream>>>(s2, s2, s2, w3s[0], w3s[1], w3s[2],
                                       2, 0, 1 | (2 << 2), 1024, 128, 1, cur);
    float* spk3 = out;
    float* mem3 = out + (size_t)M_ * NOUT;
    lif_final<<<(B_ * NOUT) / 256, blk, 0, stream>>>(cur, b3, spk3, mem3, NOUT, B_ * NOUT);
  }
}